// Round 6
// baseline (192.142 us; speedup 1.0000x reference)
//
#include <hip/hip_runtime.h>

#define IMG 1024

// entropy of a window sum s with n = 1/inv_n elements: -(p0*log2 p0 + p1*log2 p1)
__device__ __forceinline__ float ent(float s, float inv_n) {
    float p1 = s * inv_n;
    float p0 = 1.0f - p1;
    float l1 = (p1 > 0.0f) ? __log2f(p1) : 0.0f;
    float l0 = (p0 > 0.0f) ? __log2f(p0) : 0.0f;
    return -(p0 * l0 + p1 * l1);
}

__device__ __forceinline__ float bfly_sum(float v) {
#pragma unroll
    for (int m = 32; m >= 1; m >>= 1) v += __shfl_xor(v, m);
    return v;  // full 64-lane sum, broadcast
}

// Kernel 1: block = 128x256 tile (1024 blocks = 4 blocks/CU, one generation).
// Wave w = rows 32w..32w+31; thread = 4 cols. Wave processes 4 strips of 8
// rows with DOUBLE-BUFFERED loads: strip s+1's 8 contiguous 1 KiB wave-loads
// issue before strip s's epilogue runs, keeping the memory pipe continuously
// fed (loop-shaped like the 6.3 TB/s copy, unlike one-shot R2-R5).
// k2/k4 in-register; k8: shfl_xor(1); k16/k32: in-register across strips +
// shfl_xor(2)/(4). ws: [0,32K) 32x32 s32 grids/image; 32768+: block records.
__global__ __launch_bounds__(256, 4) void slice_k1(const float* __restrict__ x,
                                                   float* __restrict__ ws) {
    const int b    = blockIdx.x >> 5;   // image (32 blocks per image)
    const int tile = blockIdx.x & 31;   // 8 row-bands x 4 col-blocks
    const int R = tile >> 2, C = tile & 3;
    const int t = threadIdx.x, w = t >> 6, l = t & 63;

    const float* p = x + (size_t)b * (IMG * IMG)
                       + (size_t)(R * 128 + w * 32) * IMG + (C * 256 + l * 4);

    float4 buf[2][8];
#pragma unroll
    for (int i = 0; i < 8; ++i)
        buf[0][i] = *(const float4*)(p + (size_t)i * IMG);

    float e2 = 0.f, e4 = 0.f, e8 = 0.f;
    float s8str[4];
#pragma unroll
    for (int s = 0; s < 4; ++s) {
        if (s < 3) {                    // prefetch next strip (independent)
            const float* q = p + (size_t)(8 * (s + 1)) * IMG;
#pragma unroll
            for (int i = 0; i < 8; ++i)
                buf[(s + 1) & 1][i] = *(const float4*)(q + (size_t)i * IMG);
        }
        float4* v = buf[s & 1];
        float s4h[4];
#pragma unroll
        for (int i = 0; i < 4; ++i) {   // row pair (2i, 2i+1) of strip
            float4 a = v[2 * i], c = v[2 * i + 1];
            float s2a = a.x + a.y + c.x + c.y;
            float s2b = a.z + a.w + c.z + c.w;
            e2 += ent(s2a, 0.25f) + ent(s2b, 0.25f);
            s4h[i] = s2a + s2b;
        }
        float s4a = s4h[0] + s4h[1], s4b = s4h[2] + s4h[3];
        e4 += ent(s4a, 1.f / 16.f) + ent(s4b, 1.f / 16.f);
        float t8 = s4a + s4b;
        float s8 = t8 + __shfl_xor(t8, 1);   // 8 cols (dup x2)
        e8 += ent(s8, 1.f / 64.f);
        s8str[s] = s8;
    }
    // k=16: strips (0,1) and (2,3) in-register, cols via shfl_xor(2) (dup x4)
    float s16a = s8str[0] + s8str[1]; s16a += __shfl_xor(s16a, 2);
    float s16b = s8str[2] + s8str[3]; s16b += __shfl_xor(s16b, 2);
    float e16 = ent(s16a, 1.f / 256.f) + ent(s16b, 1.f / 256.f);
    // k=32: all 32 rows, cols via shfl_xor(4) (dup x8)
    float s32 = s16a + s16b; s32 += __shfl_xor(s32, 4);
    float e32 = ent(s32, 1.f / 1024.f);

    if ((l & 7) == 0)                   // 8 distinct s32 cells per wave
        ws[(size_t)b * 1024 + (R * 4 + w) * 32 + C * 8 + (l >> 3)] = s32;

    float E2 = bfly_sum(e2), E4 = bfly_sum(e4), E8 = bfly_sum(e8);
    float E16 = bfly_sum(e16), E32 = bfly_sum(e32);

    __shared__ float wle[4][5];
    if (l == 0) {
        wle[w][0] = E2; wle[w][1] = E4; wle[w][2] = E8 * 0.5f;
        wle[w][3] = E16 * 0.25f; wle[w][4] = E32 * 0.125f;
    }
    __syncthreads();
    if (t == 0) {
        float* rec = ws + 32768 + (size_t)blockIdx.x * 8;
#pragma unroll
        for (int j = 0; j < 5; ++j)
            rec[j] = wle[0][j] + wle[1][j] + wle[2][j] + wle[3][j];
    }
}

// Kernel 2: per-image finish (32 blocks x 256 threads). Sums 32 block
// records, then pyramids the 32x32 s32 grid -> k=64/128/256. Plain stores.
__global__ __launch_bounds__(256) void slice_k2(const float* __restrict__ ws,
                                                float* __restrict__ out) {
    const int b = blockIdx.x, t = threadIdx.x;
    const int w = t >> 6, l = t & 63;

    __shared__ float g[1024];           // s32 grid
    ((float4*)g)[t] = ((const float4*)(ws + (size_t)b * 1024))[t];

    float r0 = 0.f, r1 = 0.f, r2 = 0.f, r3 = 0.f, r4 = 0.f;
    if (t < 32) {                       // all in wave 0
        const float* rec = ws + 32768 + ((size_t)(b * 32 + t)) * 8;
        float4 a = *(const float4*)rec;
        r0 = a.x; r1 = a.y; r2 = a.z; r3 = a.w; r4 = rec[4];
    }
    r0 = bfly_sum(r0); r1 = bfly_sum(r1); r2 = bfly_sum(r2);
    r3 = bfly_sum(r3); r4 = bfly_sum(r4);
    __shared__ float wr[5];
    __shared__ float w64s[4];
    __shared__ float l64[256];
    if (t == 0) { wr[0] = r0; wr[1] = r1; wr[2] = r2; wr[3] = r3; wr[4] = r4; }
    __syncthreads();

    // k=64: 16x16 windows, one per thread
    int i = t >> 4, j = t & 15;
    float s64 = g[(2 * i) * 32 + 2 * j]     + g[(2 * i) * 32 + 2 * j + 1]
              + g[(2 * i + 1) * 32 + 2 * j] + g[(2 * i + 1) * 32 + 2 * j + 1];
    float e64 = ent(s64, 1.f / 4096.f);
    l64[t] = s64;
    float E64w = bfly_sum(e64);
    if (l == 0) w64s[w] = E64w;
    __syncthreads();

    if (w == 0) {                       // k=128 (64 windows = 64 lanes), k=256
        int i2 = l >> 3, j2 = l & 7;
        float s128 = l64[(2 * i2) * 16 + 2 * j2]     + l64[(2 * i2) * 16 + 2 * j2 + 1]
                   + l64[(2 * i2 + 1) * 16 + 2 * j2] + l64[(2 * i2 + 1) * 16 + 2 * j2 + 1];
        float e128 = ent(s128, 1.f / 16384.f);
        float E128 = bfly_sum(e128);
        float u = s128 + __shfl_xor(s128, 1);
        float s256 = u + __shfl_xor(u, 8);            // dup x4
        float e256 = ent(s256, 1.f / 65536.f);
        float E256 = bfly_sum(e256) * 0.25f;          // 16 distinct
        if (l == 0) {
            float E64 = w64s[0] + w64s[1] + w64s[2] + w64s[3];
            float* o = out + b * 8;
            o[0] = wr[0] * (1.f / 262144.f);
            o[1] = wr[1] * (1.f / 65536.f);
            o[2] = wr[2] * (1.f / 16384.f);
            o[3] = wr[3] * (1.f / 4096.f);
            o[4] = wr[4] * (1.f / 1024.f);
            o[5] = E64  * (1.f / 256.f);
            o[6] = E128 * (1.f / 64.f);
            o[7] = E256 * (1.f / 16.f);
        }
    }
}

extern "C" void kernel_launch(void* const* d_in, const int* in_sizes, int n_in,
                              void* d_out, int out_size, void* d_ws, size_t ws_size,
                              hipStream_t stream) {
    const float* x = (const float*)d_in[0];
    float* out = (float*)d_out;
    float* ws  = (float*)d_ws;  // 128 KiB grids + 32 KiB records

    slice_k1<<<32 * 32, 256, 0, stream>>>(x, ws);
    slice_k2<<<32, 256, 0, stream>>>(ws, out);
}